// Round 7
// baseline (215.729 us; speedup 1.0000x reference)
//
#include <hip/hip_runtime.h>
#include <hip/hip_bf16.h>

// out[b,o] = sum_i x[b,i]*w[o,i] + bias[o]; M=4096, N=2048, K=2048, fp32 io.
// R13: single-launch pipeline. Six gemm structures all land 42-43.5us =>
// gemm is at a shape-imposed floor (256^2 8-phase would halve CU count at
// N=2048; split-K reduction traffic exceeds the saving). Remaining lever is
// launch structure: merge cvt+gemm into ONE kernel, removing one dispatch +
// inter-dispatch gap. Grid-wide sync between phases via workspace flags:
//   - 512 blocks x 512 thr, 64KB LDS, VGPR<=128 (__launch_bounds__(512,4))
//     -> exactly 2 blocks/CU co-resident (LDS-limited), all 512 dispatch at T0.
//   - phase A: each block converts 3072 ushort8 units (bit-identical map to
//     the old cvt_both), release-stores flag[bid]=MAGIC (agent scope).
//   - spin: thread t watches flag[t] (512 threads <-> 512 flags), then
//     __threadfence() acquire before reading peers' bf16 (cross-XCD L2).
//   - flags live in d_ws: harness re-poisons ws each iteration -> flags
//     self-reset (MAGIC has distinct bytes, never a repeated-byte poison).
// Phase B: R12 gemm verbatim (128^2 tile, BK=128, chunk-XOR LDS swizzle,
// global_load_lds, XCD-aware block swizzle).

#define M_DIM 4096
#define N_DIM 2048
#define K_DIM 2048
#define BK 128
#define MAGIC 0x1F2E3D4Cu

typedef unsigned short ushort_t;
typedef __attribute__((ext_vector_type(8))) short short8;      // 8 bf16 (A/B frag)
typedef __attribute__((ext_vector_type(4))) float float4v;     // C/D frag
typedef __attribute__((ext_vector_type(8))) unsigned short ushort8;

// fp32 -> bf16 RNE (bit-identical to previous cvt_both pipeline)
__device__ __forceinline__ unsigned short f2bf_rne(float f) {
    unsigned int u = __builtin_bit_cast(unsigned int, f);
    u += 0x7FFFu + ((u >> 16) & 1u);
    return (unsigned short)(u >> 16);
}

__device__ __forceinline__ ushort8 pack8(float4v a, float4v b) {
    ushort8 r;
    r[0] = f2bf_rne(a[0]); r[1] = f2bf_rne(a[1]);
    r[2] = f2bf_rne(a[2]); r[3] = f2bf_rne(a[3]);
    r[4] = f2bf_rne(b[0]); r[5] = f2bf_rne(b[1]);
    r[6] = f2bf_rne(b[2]); r[7] = f2bf_rne(b[3]);
    return r;
}

// async global -> LDS (16B per lane; dest = wave-uniform base + lane*16)
__device__ __forceinline__ void async_load16(const void* g, void* l) {
    __builtin_amdgcn_global_load_lds(
        (const __attribute__((address_space(1))) void*)(g),
        (__attribute__((address_space(3))) void*)(l), 16, 0, 0);
}

// ---------------- merged: fp32->bf16 convert, grid sync, bf16 MFMA GEMM ----
// Grid MUST be 512 blocks x 512 threads (2/CU co-resident; flag sync).
__global__ void __launch_bounds__(512, 4)
gemm_merged(const float* __restrict__ x,
            const float* __restrict__ w,
            const float* __restrict__ bias,
            float* __restrict__ out,
            ushort_t* wsb,                 // bf16 staging (x: 8.4M, w: 4.2M elems)
            unsigned int* flags,           // 512 flags (poisoned each iter)
            int xN8) {
    // ======== Phase A: conversion (idx map identical to old cvt_both) ======
    {
        ushort8* ws8 = (ushort8*)wsb;
        const int base = (int)blockIdx.x * 3072;   // 512 blk * 3072 = totN8 exactly
#pragma unroll
        for (int k2 = 0; k2 < 6; k2++) {
            const int idx = base + k2 * 512 + (int)threadIdx.x;
            const float4v* in4 = (idx < xN8) ? (const float4v*)x + (size_t)idx * 2
                                             : (const float4v*)w + (size_t)(idx - xN8) * 2;
            float4v a = in4[0];
            float4v b = in4[1];
            ws8[idx] = pack8(a, b);
        }
        __syncthreads();   // all block's stores issued before the release
        if (threadIdx.x == 0)
            __hip_atomic_store(&flags[blockIdx.x], MAGIC,
                               __ATOMIC_RELEASE, __HIP_MEMORY_SCOPE_AGENT);
        // all 512 blocks are co-resident (2/CU, LDS-limited) -> no deadlock.
        while (!__syncthreads_and(
            __hip_atomic_load(&flags[threadIdx.x], __ATOMIC_RELAXED,
                              __HIP_MEMORY_SCOPE_AGENT) == MAGIC)) {}
        __threadfence();   // acquire: drop stale L1/L2 before reading peers' bf16
    }

    const ushort_t* xb = wsb;
    const ushort_t* wb = wsb + (size_t)M_DIM * K_DIM;

    // ======== Phase B: R12 gemm body (verbatim) ========
    __shared__ ushort_t ldsA[128 * BK];   // 32 KB
    __shared__ ushort_t ldsB[128 * BK];   // 32 KB

    const int tid  = threadIdx.x;
    const int wave = tid >> 6;
    const int lane = tid & 63;
    const int quad = lane >> 4;    // 0..3
    const int lrow = lane & 15;    // 0..15

    // XCD-aware swizzle (neutral in R12 A/B but harmless; keeps L2 sharers co-XCD)
    const int swzb = ((int)blockIdx.x & 7) * 64 + ((int)blockIdx.x >> 3);
    const int bm = swzb >> 4;    // 0..31
    const int bn = swzb & 15;    // 0..15
    const int rowBase = bm * 128;
    const int colBase = bn * 128;

    const int waveR = (wave >> 2) * 64;   // 0 or 64
    const int waveC = (wave & 3) * 32;    // 0,32,64,96

    // staging: waves 0-3 stage A rows sgrp*32..+31, waves 4-7 stage B.
    // Rows are 256B = 16 chunks of 16B; one instr covers 4 rows. Stored chunk
    // at position p of row r is p ^ (r&15): instr j lane L fetches global
    // chunk q = (L&15) ^ (L>>4) ^ ((4j)&15).
    const int  sgrp = wave & 3;
    const bool isB  = wave >= 4;
    const int  R0   = sgrp * 32;
    const int  rowl = lane >> 4;          // 0..3
    const int  qb   = (lane & 15) ^ rowl;
    const ushort_t* src = isB ? wb + (long long)colBase * K_DIM
                              : xb + (long long)rowBase * K_DIM;
    const ushort_t* g[8];
#pragma unroll
    for (int j = 0; j < 8; j++)
        g[j] = src + (long long)(R0 + 4 * j + rowl) * K_DIM + (qb ^ ((4 * j) & 15)) * 8;
    ushort_t* lbase = (isB ? ldsB : ldsA) + R0 * BK;  // wave-uniform

    // fragment read offsets: row r&15 = lrow; chunk c = kc*4 + quad stored at
    // (kc*4 ^ quad ^ lrow); ushort offset = that*8 = sw ^ (kc*32).
    const int sw = (quad ^ lrow) * 8;
    const ushort_t* aP = &ldsA[(waveR + lrow) * BK];
    const ushort_t* bP = &ldsB[(waveC + lrow) * BK];

    float4v acc[4][2] = {};

    for (int k0 = 0; k0 < K_DIM; k0 += BK) {
#pragma unroll
        for (int j = 0; j < 8; j++) {
            async_load16(g[j], lbase + (4 * j) * BK);
            g[j] += BK;
        }
        __syncthreads();

#pragma unroll
        for (int kc = 0; kc < 4; kc++) {
            const int ko = sw ^ (kc * 32);
            short8 af[4], bf[2];
#pragma unroll
            for (int mi = 0; mi < 4; mi++)
                af[mi] = *(const short8*)(aP + mi * 16 * BK + ko);
#pragma unroll
            for (int ni = 0; ni < 2; ni++)
                bf[ni] = *(const short8*)(bP + ni * 16 * BK + ko);
#pragma unroll
            for (int mi = 0; mi < 4; mi++)
#pragma unroll
                for (int ni = 0; ni < 2; ni++)
                    acc[mi][ni] = __builtin_amdgcn_mfma_f32_16x16x32_bf16(
                        af[mi], bf[ni], acc[mi][ni], 0, 0, 0);
        }
        __syncthreads();
    }

    // epilogue: C/D layout col=lane&15, row=quad*4+reg (harness-verified)
#pragma unroll
    for (int ni = 0; ni < 2; ni++) {
        const int col = colBase + waveC + ni * 16 + lrow;
        const float bv = bias[col];
#pragma unroll
        for (int mi = 0; mi < 4; mi++) {
            const int row0 = rowBase + waveR + mi * 16 + quad * 4;
            float4v v = acc[mi][ni];
#pragma unroll
            for (int i = 0; i < 4; i++)
                out[(long long)(row0 + i) * N_DIM + col] = v[i] + bv;
        }
    }
}

// ---------------- fallback (ws too small): fp32 naive ----------------
__global__ void __launch_bounds__(256) linear_naive(const float* __restrict__ x,
                                                    const float* __restrict__ w,
                                                    const float* __restrict__ bias,
                                                    float* __restrict__ out) {
    __shared__ float xs[K_DIM];
    const int b = blockIdx.y;
    const int o = blockIdx.x * 256 + threadIdx.x;
    for (int k = threadIdx.x; k < K_DIM; k += 256)
        xs[k] = x[(long long)b * K_DIM + k];
    __syncthreads();
    const float4v* wr = (const float4v*)(w + (long long)o * K_DIM);
    float s = 0.f;
    for (int k4 = 0; k4 < K_DIM / 4; k4++) {
        float4v wv = wr[k4];
        float4v xv = *(const float4v*)&xs[k4 * 4];
        s += xv[0] * wv[0] + xv[1] * wv[1] + xv[2] * wv[2] + xv[3] * wv[3];
    }
    out[(long long)b * N_DIM + o] = s + bias[o];
}

extern "C" void kernel_launch(void* const* d_in, const int* in_sizes, int n_in,
                              void* d_out, int out_size, void* d_ws, size_t ws_size,
                              hipStream_t stream) {
    const float* x    = (const float*)d_in[0];   // [4096, 2048]
    const float* w    = (const float*)d_in[1];   // [2048, 2048]
    const float* bias = (const float*)d_in[2];   // [2048]
    float* out = (float*)d_out;                  // [4096, 2048]

    const size_t xElems = (size_t)M_DIM * K_DIM;              // 8388608
    const size_t wElems = (size_t)N_DIM * K_DIM;              // 4194304
    const size_t bfBytes = (xElems + wElems) * sizeof(ushort_t);  // 25165824
    const size_t need = bfBytes + 512 * sizeof(unsigned int);

    if (ws_size >= need) {
        ushort_t* wsb = (ushort_t*)d_ws;
        unsigned int* flags = (unsigned int*)((char*)d_ws + bfBytes);
        const int xN8 = (int)(xElems / 8);
        gemm_merged<<<(M_DIM / 128) * (N_DIM / 128), 512, 0, stream>>>(
            x, w, bias, out, wsb, flags, xN8);
    } else {
        dim3 grid(N_DIM / 256, M_DIM);
        linear_naive<<<grid, 256, 0, stream>>>(x, w, bias, out);
    }
}

// Round 8
// 131.546 us; speedup vs baseline: 1.6400x; 1.6400x over previous
//
#include <hip/hip_runtime.h>
#include <hip/hip_bf16.h>

// out[b,o] = sum_i x[b,i]*w[o,i] + bias[o]; M=4096, N=2048, K=2048, fp32 io.
// R14: restore session-best (R12, 130.3us measured). R13's single-launch
// fusion regressed to 215.7us (merged kernel 150us: MfmaUtil 9%, VALU 6% --
// time went into the 512-block flag-spin + cross-XCD acquire, not work).
// Final structure: cvt (HBM-roofline, 12.5us) + gemm (818 TF, the verified
// ceiling of the 128^2 global_load_lds structure at this shape; 256^2/8-phase
// and split-K are arithmetically net-negative at N=2048). Ledger: schedule
// (R8), LDS traffic (R9), XCD swizzle (R12) all neutral; fetch x2 (R10),
// epilogue split (R11), fusion (R13) all regressions.

#define M_DIM 4096
#define N_DIM 2048
#define K_DIM 2048
#define BK 128

typedef unsigned short ushort_t;
typedef __attribute__((ext_vector_type(8))) short short8;      // 8 bf16 (A/B frag)
typedef __attribute__((ext_vector_type(4))) float float4v;     // C/D frag
typedef __attribute__((ext_vector_type(8))) unsigned short ushort8;

// ---------------- fp32 -> bf16 (RNE), x and w fused in one launch ----------------
__device__ __forceinline__ unsigned short f2bf_rne(float f) {
    unsigned int u = __builtin_bit_cast(unsigned int, f);
    u += 0x7FFFu + ((u >> 16) & 1u);
    return (unsigned short)(u >> 16);
}

__global__ void __launch_bounds__(256) cvt_both(const float* __restrict__ x,
                                                const float* __restrict__ w,
                                                ushort8* __restrict__ ws8,
                                                int xN8, int totN8) {
    int idx = blockIdx.x * 256 + threadIdx.x;
    if (idx >= totN8) return;
    const float4v* in4 = (idx < xN8) ? (const float4v*)x + (size_t)idx * 2
                                     : (const float4v*)w + (size_t)(idx - xN8) * 2;
    float4v a = in4[0];
    float4v b = in4[1];
    ushort8 r;
    r[0] = f2bf_rne(a[0]); r[1] = f2bf_rne(a[1]);
    r[2] = f2bf_rne(a[2]); r[3] = f2bf_rne(a[3]);
    r[4] = f2bf_rne(b[0]); r[5] = f2bf_rne(b[1]);
    r[6] = f2bf_rne(b[2]); r[7] = f2bf_rne(b[3]);
    ws8[idx] = r;
}

// ---------------- async global -> LDS (16B per lane; dest = base + lane*16) ----
__device__ __forceinline__ void async_load16(const void* g, void* l) {
    __builtin_amdgcn_global_load_lds(
        (const __attribute__((address_space(1))) void*)(g),
        (__attribute__((address_space(3))) void*)(l), 16, 0, 0);
}

// ---------------- bf16 MFMA GEMM, C = Xb * Wb^T + bias ----------------
// Xb: [M,K] bf16 row-major, Wb: [N,K] bf16 row-major.
// Block: 128x128 tile, 512 threads = 8 waves in 2(row) x 4(col); wave-tile 64x32.
__global__ void __launch_bounds__(512) gemm_bf16(const ushort_t* __restrict__ xb,
                                                 const ushort_t* __restrict__ wb,
                                                 const float* __restrict__ bias,
                                                 float* __restrict__ out) {
    __shared__ ushort_t ldsA[128 * BK];   // 32 KB
    __shared__ ushort_t ldsB[128 * BK];   // 32 KB

    const int tid  = threadIdx.x;
    const int wave = tid >> 6;
    const int lane = tid & 63;
    const int quad = lane >> 4;    // 0..3
    const int lrow = lane & 15;    // 0..15

    // XCD-aware swizzle. 512 blocks, 8 XCDs, 512%8==0 -> bijective.
    const int swzb = ((int)blockIdx.x & 7) * 64 + ((int)blockIdx.x >> 3);
    const int bm = swzb >> 4;    // 0..31
    const int bn = swzb & 15;    // 0..15
    const int rowBase = bm * 128;
    const int colBase = bn * 128;

    const int waveR = (wave >> 2) * 64;   // 0 or 64
    const int waveC = (wave & 3) * 32;    // 0,32,64,96

    // ---- staging: waves 0-3 stage A rows sgrp*32..+31, waves 4-7 stage B ----
    // Rows are 256B = 16 chunks of 16B; one instr covers 4 rows.
    // HW places lane L at row_local L>>4, position L&15. Stored chunk at
    // position p of row r is p ^ (r&15), so instr j (rows R0+4j..+3) lane L
    // fetches global chunk q = (L&15) ^ (L>>4) ^ ((4j)&15).
    const int  sgrp = wave & 3;
    const bool isB  = wave >= 4;
    const int  R0   = sgrp * 32;
    const int  rowl = lane >> 4;          // 0..3
    const int  qb   = (lane & 15) ^ rowl;
    const ushort_t* src = isB ? wb + (long long)colBase * K_DIM
                              : xb + (long long)rowBase * K_DIM;
    const ushort_t* g[8];
#pragma unroll
    for (int j = 0; j < 8; j++)
        g[j] = src + (long long)(R0 + 4 * j + rowl) * K_DIM + (qb ^ ((4 * j) & 15)) * 8;
    ushort_t* lbase = (isB ? ldsB : ldsA) + R0 * BK;  // wave-uniform

    // ---- fragment read offsets ----
    // Row r = waveR/C + mi*16 + lrow -> r&15 = lrow. Chunk c = kc*4 + quad,
    // stored at (kc*4 ^ quad ^ lrow); ushort offset = that * 8 = sw ^ (kc*32).
    const int sw = (quad ^ lrow) * 8;
    const ushort_t* aP = &ldsA[(waveR + lrow) * BK];
    const ushort_t* bP = &ldsB[(waveC + lrow) * BK];

    float4v acc[4][2] = {};

    for (int k0 = 0; k0 < K_DIM; k0 += BK) {
#pragma unroll
        for (int j = 0; j < 8; j++) {
            async_load16(g[j], lbase + (4 * j) * BK);
            g[j] += BK;
        }
        __syncthreads();

#pragma unroll
        for (int kc = 0; kc < 4; kc++) {
            const int ko = sw ^ (kc * 32);
            short8 af[4], bf[2];
#pragma unroll
            for (int mi = 0; mi < 4; mi++)
                af[mi] = *(const short8*)(aP + mi * 16 * BK + ko);
#pragma unroll
            for (int ni = 0; ni < 2; ni++)
                bf[ni] = *(const short8*)(bP + ni * 16 * BK + ko);
#pragma unroll
            for (int mi = 0; mi < 4; mi++)
#pragma unroll
                for (int ni = 0; ni < 2; ni++)
                    acc[mi][ni] = __builtin_amdgcn_mfma_f32_16x16x32_bf16(
                        af[mi], bf[ni], acc[mi][ni], 0, 0, 0);
        }
        __syncthreads();
    }

    // ---- epilogue: C/D layout col=lane&15, row=quad*4+reg ----
#pragma unroll
    for (int ni = 0; ni < 2; ni++) {
        const int col = colBase + waveC + ni * 16 + lrow;
        const float bv = bias[col];
#pragma unroll
        for (int mi = 0; mi < 4; mi++) {
            const int row0 = rowBase + waveR + mi * 16 + quad * 4;
            float4v v = acc[mi][ni];
#pragma unroll
            for (int i = 0; i < 4; i++)
                out[(long long)(row0 + i) * N_DIM + col] = v[i] + bv;
        }
    }
}

// ---------------- fallback (ws too small): fp32 naive ----------------
__global__ void __launch_bounds__(256) linear_naive(const float* __restrict__ x,
                                                    const float* __restrict__ w,
                                                    const float* __restrict__ bias,
                                                    float* __restrict__ out) {
    __shared__ float xs[K_DIM];
    const int b = blockIdx.y;
    const int o = blockIdx.x * 256 + threadIdx.x;
    for (int k = threadIdx.x; k < K_DIM; k += 256)
        xs[k] = x[(long long)b * K_DIM + k];
    __syncthreads();
    const float4v* wr = (const float4v*)(w + (long long)o * K_DIM);
    float s = 0.f;
    for (int k4 = 0; k4 < K_DIM / 4; k4++) {
        float4v wv = wr[k4];
        float4v xv = *(const float4v*)&xs[k4 * 4];
        s += xv[0] * wv[0] + xv[1] * wv[1] + xv[2] * wv[2] + xv[3] * wv[3];
    }
    out[(long long)b * N_DIM + o] = s + bias[o];
}

extern "C" void kernel_launch(void* const* d_in, const int* in_sizes, int n_in,
                              void* d_out, int out_size, void* d_ws, size_t ws_size,
                              hipStream_t stream) {
    const float* x    = (const float*)d_in[0];   // [4096, 2048]
    const float* w    = (const float*)d_in[1];   // [2048, 2048]
    const float* bias = (const float*)d_in[2];   // [2048]
    float* out = (float*)d_out;                  // [4096, 2048]

    const size_t xElems = (size_t)M_DIM * K_DIM;   // 8388608
    const size_t wElems = (size_t)N_DIM * K_DIM;   // 4194304
    const size_t need = (xElems + wElems) * sizeof(ushort_t);  // ~25.2 MB

    if (ws_size >= need) {
        ushort_t* xb = (ushort_t*)d_ws;
        ushort_t* wb = xb + xElems;
        const int xN8 = (int)(xElems / 8);
        const int totN8 = (int)((xElems + wElems) / 8);
        cvt_both<<<(totN8 + 255) / 256, 256, 0, stream>>>(x, w, (ushort8*)d_ws, xN8, totN8);
        gemm_bf16<<<(M_DIM / 128) * (N_DIM / 128), 512, 0, stream>>>(xb, wb, bias, out);
    } else {
        dim3 grid(N_DIM / 256, M_DIM);
        linear_naive<<<grid, 256, 0, stream>>>(x, w, bias, out);
    }
}